// Round 8
// baseline (167.806 us; speedup 1.0000x reference)
//
#include <hip/hip_runtime.h>

// HopfRNNCellTheta: T=64 < UNITS=1024 -> z[:,0] stays 0 -> A unused,
// y_t = 0.5*(B@x_t). Output = REAL part only, float32[64][1024][1024].
// out[t][n][u] = ReY[s][n], s = t+u-1023, if s>=0 else 0.
//
// Fused single kernel (r6 structure, best known), gemv critical path cut:
//  - 512-thread blocks. blocks [0,128): gemv, 8 waves = 8 n-rows each;
//    x chunk staged as float2 (re,im) transposed [m][t], stride 67 (CF);
//    register double-buffer prefetch depth 2; B per-chunk via wave-uniform
//    LDS float4. Then band write (s>=0 cells).
//  - blocks [128,1024): persistent zero-fill of all s<0 words (r6 logic).
// Every output byte written exactly once (byte-exact partition).

#define NDIM 1024

__global__ __launch_bounds__(512) void hopf_fused(
    const float* __restrict__ x_re, const float* __restrict__ x_im,
    const float* __restrict__ B_re, const float* __restrict__ B_im,
    float* __restrict__ out) {
  __shared__ float2 xs[64][67];   // xs[m][t] = (re,im); stride 67 -> CF banks
  __shared__ float bs1[8][68];
  __shared__ float bs2[8][68];
  const int tid = threadIdx.x;

  if (blockIdx.x >= 128) {
    // ---------- persistent zero-fill (out-of-band words only) ----------
    float4* out4 = (float4*)out;
    const float4 z = make_float4(0.f, 0.f, 0.f, 0.f);
    const int stride = 896 * 512;
    for (int q = (int)(blockIdx.x - 128) * 512 + tid; q < (1 << 24);
         q += stride) {
      const int t = q >> 18;
      const int u4 = q & 255;
      const int sb = t + 4 * u4 - 1023;      // s of word component 0
      if (sb <= -4) {                         // fully out of band (~97%)
        out4[q] = z;
      } else if (sb < 0) {                    // boundary word: mixed bytes
        float* p = out + ((long long)q << 2);
        p[0] = 0.f;
        if (sb + 1 < 0) p[1] = 0.f;
        if (sb + 2 < 0) p[2] = 0.f;           // sb+3 >= 0 always here
      }
    }
    return;
  }

  // ---------- gemv: wave ng -> n = blk*8+ng, lane = t ----------
  __builtin_amdgcn_s_setprio(1);
  const int t = tid & 63;
  const int ng = tid >> 6;
  const int n = blockIdx.x * 8 + ng;
  const int str = tid >> 3;                   // staging t-row (0..63)
  const int sj = (tid & 7) * 8;               // staging m-offset (0,8,..,56)
  const float* xr_base = x_re + str * NDIM + sj;
  const float* xi_base = x_im + str * NDIM + sj;
  const float* brow_re = B_re + n * NDIM + t;
  const float* brow_im = B_im + n * NDIM + t;

  // two register prefetch buffers (depth 2)
  float4 Ar0[2], Ai0[2], Ar1[2], Ai1[2];
  float b0r, b0i, b1r, b1i;
  float a1 = 0.f, a2 = 0.f;

#define LOADBUF(AR, AI, BRV, BIV, M0)                                   \
  do {                                                                  \
    AR[0] = *(const float4*)(xr_base + (M0));                           \
    AR[1] = *(const float4*)(xr_base + (M0) + 4);                       \
    AI[0] = *(const float4*)(xi_base + (M0));                           \
    AI[1] = *(const float4*)(xi_base + (M0) + 4);                       \
    BRV = brow_re[(M0)];                                                \
    BIV = brow_im[(M0)];                                                \
  } while (0)

#define STAGE(AR, AI, BRV, BIV)                                         \
  do {                                                                  \
    xs[sj + 0][str] = make_float2(AR[0].x, AI[0].x);                    \
    xs[sj + 1][str] = make_float2(AR[0].y, AI[0].y);                    \
    xs[sj + 2][str] = make_float2(AR[0].z, AI[0].z);                    \
    xs[sj + 3][str] = make_float2(AR[0].w, AI[0].w);                    \
    xs[sj + 4][str] = make_float2(AR[1].x, AI[1].x);                    \
    xs[sj + 5][str] = make_float2(AR[1].y, AI[1].y);                    \
    xs[sj + 6][str] = make_float2(AR[1].z, AI[1].z);                    \
    xs[sj + 7][str] = make_float2(AR[1].w, AI[1].w);                    \
    bs1[ng][t] = BRV;                                                   \
    bs2[ng][t] = BIV;                                                   \
  } while (0)

#define COMPUTE()                                                       \
  do {                                                                  \
    _Pragma("unroll")                                                   \
    for (int m4 = 0; m4 < 16; ++m4) {                                   \
      const float4 b1 = *(const float4*)&bs1[ng][m4 * 4];               \
      const float4 b2 = *(const float4*)&bs2[ng][m4 * 4];               \
      const int mm = m4 * 4;                                            \
      float2 x0 = xs[mm + 0][t];                                        \
      float2 x1 = xs[mm + 1][t];                                        \
      float2 x2 = xs[mm + 2][t];                                        \
      float2 x3 = xs[mm + 3][t];                                        \
      a1 = fmaf(b1.x, x0.x, a1); a2 = fmaf(b2.x, x0.y, a2);             \
      a1 = fmaf(b1.y, x1.x, a1); a2 = fmaf(b2.y, x1.y, a2);             \
      a1 = fmaf(b1.z, x2.x, a1); a2 = fmaf(b2.z, x2.y, a2);             \
      a1 = fmaf(b1.w, x3.x, a1); a2 = fmaf(b2.w, x3.y, a2);             \
    }                                                                   \
  } while (0)

  LOADBUF(Ar0, Ai0, b0r, b0i, 0);
  LOADBUF(Ar1, Ai1, b1r, b1i, 64);

#pragma unroll 1
  for (int c = 0; c < 16; c += 2) {
    // phase A: chunk c (buffer 0)
    STAGE(Ar0, Ai0, b0r, b0i);
    __syncthreads();
    if (c + 2 < 16) LOADBUF(Ar0, Ai0, b0r, b0i, (c + 2) * 64);
    COMPUTE();
    __syncthreads();
    // phase B: chunk c+1 (buffer 1)
    STAGE(Ar1, Ai1, b1r, b1i);
    __syncthreads();
    if (c + 3 < 16) LOADBUF(Ar1, Ai1, b1r, b1i, (c + 3) * 64);
    COMPUTE();
    __syncthreads();
  }

  // ---------- band write: lane t holds ReY[t][n] ----------
  const float yv = 0.5f * (a1 - a2);
  const long long rowoff = (long long)(n << 10);
  for (int tt = t; tt < 64; ++tt) {
    out[((long long)tt << 20) + rowoff + (1023 - tt) + t] = yv;
  }
}

extern "C" void kernel_launch(void* const* d_in, const int* in_sizes, int n_in,
                              void* d_out, int out_size, void* d_ws, size_t ws_size,
                              hipStream_t stream) {
  (void)in_sizes; (void)n_in; (void)out_size; (void)d_ws; (void)ws_size;
  const float* x_re = (const float*)d_in[0];
  const float* x_im = (const float*)d_in[1];
  const float* B_re = (const float*)d_in[4];
  const float* B_im = (const float*)d_in[5];
  hopf_fused<<<1024, 512, 0, stream>>>(x_re, x_im, B_re, B_im, (float*)d_out);
}

// Round 9
// 76.774 us; speedup vs baseline: 2.1857x; 2.1857x over previous
//
#include <hip/hip_runtime.h>

// HopfRNNCellTheta: T=64 < UNITS=1024 -> z[:,0] stays 0 -> A unused,
// y_t = 0.5*(B@x_t). Output = REAL part only, float32[64][1024][1024].
// out[t][n][u] = ReY[s][n], s = t+u-1023, if s>=0 else 0.
//
// r8 lesson: barrier-phased global->LDS gemv is stall-bound (~95% idle) under
// the fill's store flood. New gemv: x pre-transposed to xT[m][t] (K0) so lane t
// reads x coalesced straight from L2; B rows staged ONCE into wave-private LDS
// (broadcast reads); no barriers in the main loop; waves independent.
//  K1 grid 1024x256: blocks [0,128) gemv (4 waves x 2 n-rows), [128,1024)
//  persistent zero-fill of all s<0 words (r6's proven byte-exact partition).

#define NDIM 1024

// ---- K0: xT[m][t] = (x_re[t][m], x_im[t][m]); 16 blocks, LDS transpose ----
__global__ __launch_bounds__(256) void transpose_x(
    const float* __restrict__ x_re, const float* __restrict__ x_im,
    float2* __restrict__ xT) {
  __shared__ float s1[64][65];
  __shared__ float s2[64][65];
  const int tid = threadIdx.x;
  const int m0 = blockIdx.x * 64;
#pragma unroll
  for (int k = 0; k < 16; ++k) {           // coalesced reads
    const int s = tid + k * 256;
    const int tr = s >> 6, j = s & 63;
    s1[tr][j] = x_re[tr * NDIM + m0 + j];
    s2[tr][j] = x_im[tr * NDIM + m0 + j];
  }
  __syncthreads();
#pragma unroll
  for (int k = 0; k < 16; ++k) {           // coalesced writes, CF LDS reads
    const int s = tid + k * 256;
    const int ml = s >> 6, t = s & 63;
    xT[(m0 + ml) * 64 + t] = make_float2(s1[t][ml], s2[t][ml]);
  }
}

// ---- K1: fused gemv + zero-fill ----
__global__ __launch_bounds__(256) void hopf_fused2(
    const float2* __restrict__ xT,
    const float* __restrict__ B_re, const float* __restrict__ B_im,
    float* __restrict__ out) {
  __shared__ float bsR[4][2][1024];
  __shared__ float bsI[4][2][1024];
  const int tid = threadIdx.x;

  if (blockIdx.x >= 128) {
    // ---------- persistent zero-fill (out-of-band words only; r6 logic) ----
    float4* out4 = (float4*)out;
    const float4 z = make_float4(0.f, 0.f, 0.f, 0.f);
    const int stride = 896 * 256;
    for (int q = (int)(blockIdx.x - 128) * 256 + tid; q < (1 << 24);
         q += stride) {
      const int t = q >> 18;
      const int u4 = q & 255;
      const int sb = t + 4 * u4 - 1023;    // s of word component 0
      if (sb <= -4) {                       // fully out of band (~97%)
        out4[q] = z;
      } else if (sb < 0) {                  // boundary word: mixed bytes
        float* p = out + ((long long)q << 2);
        p[0] = 0.f;
        if (sb + 1 < 0) p[1] = 0.f;
        if (sb + 2 < 0) p[2] = 0.f;         // sb+3 >= 0 always here
      }
    }
    return;
  }

  // ---------- gemv: wave w -> rows n0 = blk*8+2w, n0+1; lane = t ----------
  __builtin_amdgcn_s_setprio(1);
  const int t = tid & 63;
  const int w = tid >> 6;
  const int n0 = blockIdx.x * 8 + w * 2;

  // stage both B rows into wave-private LDS (once; coalesced float4)
#pragma unroll
  for (int r = 0; r < 2; ++r) {
    const float* pR = B_re + (n0 + r) * NDIM;
    const float* pI = B_im + (n0 + r) * NDIM;
#pragma unroll
    for (int q = 0; q < 4; ++q) {
      const int m = q * 256 + t * 4;
      *(float4*)&bsR[w][r][m] = *(const float4*)(pR + m);
      *(float4*)&bsI[w][r][m] = *(const float4*)(pI + m);
    }
  }
  __syncthreads();   // single barrier: publish LDS writes

  float a1_0 = 0.f, a2_0 = 0.f, a1_1 = 0.f, a2_1 = 0.f;
  const float2* xp = xT + t;

#pragma unroll 1
  for (int m0 = 0; m0 < 1024; m0 += 16) {
    float2 xv[16];
#pragma unroll
    for (int j = 0; j < 16; ++j) xv[j] = xp[(m0 + j) * 64];  // coalesced b64
#pragma unroll
    for (int q = 0; q < 4; ++q) {
      const float4 br0 = *(const float4*)&bsR[w][0][m0 + q * 4];  // broadcast
      const float4 bi0 = *(const float4*)&bsI[w][0][m0 + q * 4];
      const float4 br1 = *(const float4*)&bsR[w][1][m0 + q * 4];
      const float4 bi1 = *(const float4*)&bsI[w][1][m0 + q * 4];
      const float2 x0 = xv[q * 4 + 0], x1 = xv[q * 4 + 1];
      const float2 x2 = xv[q * 4 + 2], x3 = xv[q * 4 + 3];
      a1_0 = fmaf(br0.x, x0.x, a1_0); a2_0 = fmaf(bi0.x, x0.y, a2_0);
      a1_0 = fmaf(br0.y, x1.x, a1_0); a2_0 = fmaf(bi0.y, x1.y, a2_0);
      a1_0 = fmaf(br0.z, x2.x, a1_0); a2_0 = fmaf(bi0.z, x2.y, a2_0);
      a1_0 = fmaf(br0.w, x3.x, a1_0); a2_0 = fmaf(bi0.w, x3.y, a2_0);
      a1_1 = fmaf(br1.x, x0.x, a1_1); a2_1 = fmaf(bi1.x, x0.y, a2_1);
      a1_1 = fmaf(br1.y, x1.x, a1_1); a2_1 = fmaf(bi1.y, x1.y, a2_1);
      a1_1 = fmaf(br1.z, x2.x, a1_1); a2_1 = fmaf(bi1.z, x2.y, a2_1);
      a1_1 = fmaf(br1.w, x3.x, a1_1); a2_1 = fmaf(bi1.w, x3.y, a2_1);
    }
  }

  // ---------- band write: lane t holds ReY[t][n0], ReY[t][n0+1] ----------
  const float yv0 = 0.5f * (a1_0 - a2_0);
  const float yv1 = 0.5f * (a1_1 - a2_1);
  const long long ro0 = (long long)(n0 << 10);
  for (int tt = t; tt < 64; ++tt) {
    const long long po = ((long long)tt << 20) + (1023 - tt) + t;
    out[po + ro0] = yv0;
    out[po + ro0 + 1024] = yv1;
  }
}

// ---- fallback (round-6 fused, known-passing; used only if ws too small) ----
__global__ __launch_bounds__(256) void hopf_fused_fb(
    const float* __restrict__ x_re, const float* __restrict__ x_im,
    const float* __restrict__ B_re, const float* __restrict__ B_im,
    float* __restrict__ out) {
  __shared__ float s1[64][65];
  __shared__ float s2[64][65];
  const int tid = threadIdx.x;
  if (blockIdx.x >= 256) {
    float4* out4 = (float4*)out;
    const float4 z = make_float4(0.f, 0.f, 0.f, 0.f);
    const int stride = 768 * 256;
    for (int q = (int)(blockIdx.x - 256) * 256 + tid; q < (1 << 24);
         q += stride) {
      const int t = q >> 18;
      const int u4 = q & 255;
      const int sb = t + 4 * u4 - 1023;
      if (sb <= -4) {
        out4[q] = z;
      } else if (sb < 0) {
        float* p = out + ((long long)q << 2);
        p[0] = 0.f;
        if (sb + 1 < 0) p[1] = 0.f;
        if (sb + 2 < 0) p[2] = 0.f;
      }
    }
    return;
  }
  const int t = tid & 63;
  const int ng = tid >> 6;
  const int n = blockIdx.x * 4 + ng;
  const float* p1 = B_re + n * NDIM;
  const float* p2 = B_im + n * NDIM;
  float a1 = 0.f, a2 = 0.f;
  for (int m0 = 0; m0 < NDIM; m0 += 64) {
    __syncthreads();
#pragma unroll
    for (int k = 0; k < 16; ++k) {
      const int s = tid + k * 256;
      const int tr2 = s >> 6, j = s & 63;
      s1[tr2][j] = x_re[tr2 * NDIM + m0 + j];
      s2[tr2][j] = x_im[tr2 * NDIM + m0 + j];
    }
    __syncthreads();
#pragma unroll 16
    for (int mm = 0; mm < 64; ++mm) {
      a1 = fmaf(p1[m0 + mm], s1[t][mm], a1);
      a2 = fmaf(p2[m0 + mm], s2[t][mm], a2);
    }
  }
  const float yv = 0.5f * (a1 - a2);
  const long long rowoff = (long long)(n << 10);
  for (int tt = t; tt < 64; ++tt) {
    out[((long long)tt << 20) + rowoff + (1023 - tt) + t] = yv;
  }
}

extern "C" void kernel_launch(void* const* d_in, const int* in_sizes, int n_in,
                              void* d_out, int out_size, void* d_ws, size_t ws_size,
                              hipStream_t stream) {
  (void)in_sizes; (void)n_in; (void)out_size;
  const float* x_re = (const float*)d_in[0];
  const float* x_im = (const float*)d_in[1];
  const float* B_re = (const float*)d_in[4];
  const float* B_im = (const float*)d_in[5];
  float* out = (float*)d_out;

  if (ws_size >= (size_t)(64 * NDIM * sizeof(float2))) {
    float2* xT = (float2*)d_ws;   // [1024 m][64 t], 512 KB
    transpose_x<<<16, 256, 0, stream>>>(x_re, x_im, xT);
    hopf_fused2<<<1024, 256, 0, stream>>>(xT, B_re, B_im, out);
  } else {
    hopf_fused_fb<<<1024, 256, 0, stream>>>(x_re, x_im, B_re, B_im, out);
  }
}

// Round 10
// 71.381 us; speedup vs baseline: 2.3509x; 1.0756x over previous
//
#include <hip/hip_runtime.h>

// HopfRNNCellTheta: T=64 < UNITS=1024 -> z[:,0] stays 0 -> A unused,
// y_t = 0.5*(B@x_t). Output = REAL part only, float32[64][1024][1024].
// out[t][n][u] = ReY[s][n], s = t+u-1023, if s>=0 else 0.
//
// r10 = r6 shell (256 gemv + 768 fill blocks, 32KB LDS, proven byte-exact
// fill partition, coalesced wave-uniform band write) + r9 core (x transposed
// by K0 so lane t reads x coalesced from L2; B row staged ONCE in
// wave-private LDS -> zero barriers anywhere in the gemv; ping-pong register
// prefetch keeps one 16-m chunk in flight).

#define NDIM 1024

// ---- K0: xT[m][t] = (x_re[t][m], x_im[t][m]); 16 blocks, LDS transpose ----
__global__ __launch_bounds__(256) void transpose_x(
    const float* __restrict__ x_re, const float* __restrict__ x_im,
    float2* __restrict__ xT) {
  __shared__ float s1[64][65];
  __shared__ float s2[64][65];
  const int tid = threadIdx.x;
  const int m0 = blockIdx.x * 64;
#pragma unroll
  for (int k = 0; k < 16; ++k) {           // coalesced reads
    const int s = tid + k * 256;
    const int tr = s >> 6, j = s & 63;
    s1[tr][j] = x_re[tr * NDIM + m0 + j];
    s2[tr][j] = x_im[tr * NDIM + m0 + j];
  }
  __syncthreads();
#pragma unroll
  for (int k = 0; k < 16; ++k) {           // coalesced writes, CF LDS reads
    const int s = tid + k * 256;
    const int ml = s >> 6, t = s & 63;
    xT[(m0 + ml) * 64 + t] = make_float2(s1[t][ml], s2[t][ml]);
  }
}

// ---- K1: fused gemv + zero-fill ----
__global__ __launch_bounds__(256) void hopf_fused3(
    const float2* __restrict__ xT,
    const float* __restrict__ B_re, const float* __restrict__ B_im,
    float* __restrict__ out) {
  __shared__ float bsR[4][1024];   // wave-private B rows (re)
  __shared__ float bsI[4][1024];   // wave-private B rows (im)
  const int tid = threadIdx.x;

  if (blockIdx.x >= 256) {
    // ---------- persistent zero-fill (r6-proven, byte-exact) ----------
    float4* out4 = (float4*)out;
    const float4 z = make_float4(0.f, 0.f, 0.f, 0.f);
    const int stride = 768 * 256;
    for (int q = (int)(blockIdx.x - 256) * 256 + tid; q < (1 << 24);
         q += stride) {
      const int t = q >> 18;
      const int u4 = q & 255;
      const int sb = t + 4 * u4 - 1023;    // s of word component 0
      if (sb <= -4) {                       // fully out of band (~97%)
        out4[q] = z;
      } else if (sb < 0) {                  // boundary word: mixed bytes
        float* p = out + ((long long)q << 2);
        p[0] = 0.f;
        if (sb + 1 < 0) p[1] = 0.f;
        if (sb + 2 < 0) p[2] = 0.f;         // sb+3 >= 0 always here
      }
    }
    return;
  }

  // ---------- gemv: wave w -> row n = blk*4 + w; lane = t ----------
  __builtin_amdgcn_s_setprio(1);
  const int t = tid & 63;
  const int w = tid >> 6;
  const int n = blockIdx.x * 4 + w;

  // stage the B row once into wave-private LDS. No __syncthreads needed:
  // only this wave reads this region; same-wave ds_write->ds_read ordering
  // is enforced by compiler-inserted s_waitcnt lgkmcnt.
  {
    const float* pR = B_re + n * NDIM;
    const float* pI = B_im + n * NDIM;
#pragma unroll
    for (int q = 0; q < 4; ++q) {
      const int m = q * 256 + t * 4;
      *(float4*)&bsR[w][m] = *(const float4*)(pR + m);
      *(float4*)&bsI[w][m] = *(const float4*)(pI + m);
    }
  }

  float a1 = 0.f, a2 = 0.f;
  const float2* xp = xT + t;
  float2 xv[16], xn[16];

#define COMP(X, MB)                                                     \
  do {                                                                  \
    _Pragma("unroll")                                                   \
    for (int q = 0; q < 4; ++q) {                                       \
      const float4 br = *(const float4*)&bsR[w][(MB) + q * 4];          \
      const float4 bi = *(const float4*)&bsI[w][(MB) + q * 4];          \
      a1 = fmaf(br.x, X[q * 4 + 0].x, a1);                              \
      a2 = fmaf(bi.x, X[q * 4 + 0].y, a2);                              \
      a1 = fmaf(br.y, X[q * 4 + 1].x, a1);                              \
      a2 = fmaf(bi.y, X[q * 4 + 1].y, a2);                              \
      a1 = fmaf(br.z, X[q * 4 + 2].x, a1);                              \
      a2 = fmaf(bi.z, X[q * 4 + 2].y, a2);                              \
      a1 = fmaf(br.w, X[q * 4 + 3].x, a1);                              \
      a2 = fmaf(bi.w, X[q * 4 + 3].y, a2);                              \
    }                                                                   \
  } while (0)

#pragma unroll
  for (int j = 0; j < 16; ++j) xv[j] = xp[j * 64];   // chunk 0 in flight

#pragma unroll 1
  for (int m0 = 0; m0 < 1024; m0 += 32) {
#pragma unroll
    for (int j = 0; j < 16; ++j) xn[j] = xp[(m0 + 16 + j) * 64];
    COMP(xv, m0);
    if (m0 + 32 < 1024) {
#pragma unroll
      for (int j = 0; j < 16; ++j) xv[j] = xp[(m0 + 32 + j) * 64];
    }
    COMP(xn, m0 + 16);
  }

  // ---------- band write: wave-uniform tt -> coalesced bursts ----------
  const float yv = 0.5f * (a1 - a2);
  const long long rowoff = (long long)n << 10;
  for (int tt = 0; tt < 64; ++tt) {
    if (t <= tt) {
      out[((long long)tt << 20) + rowoff + (1023 - tt) + t] = yv;
    }
  }
}

// ---- fallback (round-6 fused, known-passing; used only if ws too small) ----
__global__ __launch_bounds__(256) void hopf_fused_fb(
    const float* __restrict__ x_re, const float* __restrict__ x_im,
    const float* __restrict__ B_re, const float* __restrict__ B_im,
    float* __restrict__ out) {
  __shared__ float s1[64][65];
  __shared__ float s2[64][65];
  const int tid = threadIdx.x;
  if (blockIdx.x >= 256) {
    float4* out4 = (float4*)out;
    const float4 z = make_float4(0.f, 0.f, 0.f, 0.f);
    const int stride = 768 * 256;
    for (int q = (int)(blockIdx.x - 256) * 256 + tid; q < (1 << 24);
         q += stride) {
      const int t = q >> 18;
      const int u4 = q & 255;
      const int sb = t + 4 * u4 - 1023;
      if (sb <= -4) {
        out4[q] = z;
      } else if (sb < 0) {
        float* p = out + ((long long)q << 2);
        p[0] = 0.f;
        if (sb + 1 < 0) p[1] = 0.f;
        if (sb + 2 < 0) p[2] = 0.f;
      }
    }
    return;
  }
  const int t = tid & 63;
  const int ng = tid >> 6;
  const int n = blockIdx.x * 4 + ng;
  const float* p1 = B_re + n * NDIM;
  const float* p2 = B_im + n * NDIM;
  float a1 = 0.f, a2 = 0.f;
  for (int m0 = 0; m0 < NDIM; m0 += 64) {
    __syncthreads();
#pragma unroll
    for (int k = 0; k < 16; ++k) {
      const int s = tid + k * 256;
      const int tr2 = s >> 6, j = s & 63;
      s1[tr2][j] = x_re[tr2 * NDIM + m0 + j];
      s2[tr2][j] = x_im[tr2 * NDIM + m0 + j];
    }
    __syncthreads();
#pragma unroll 16
    for (int mm = 0; mm < 64; ++mm) {
      a1 = fmaf(p1[m0 + mm], s1[t][mm], a1);
      a2 = fmaf(p2[m0 + mm], s2[t][mm], a2);
    }
  }
  const float yv = 0.5f * (a1 - a2);
  const long long rowoff = (long long)(n << 10);
  for (int tt = 0; tt < 64; ++tt) {
    if (t <= tt) {
      out[((long long)tt << 20) + rowoff + (1023 - tt) + t] = yv;
    }
  }
}

extern "C" void kernel_launch(void* const* d_in, const int* in_sizes, int n_in,
                              void* d_out, int out_size, void* d_ws, size_t ws_size,
                              hipStream_t stream) {
  (void)in_sizes; (void)n_in; (void)out_size;
  const float* x_re = (const float*)d_in[0];
  const float* x_im = (const float*)d_in[1];
  const float* B_re = (const float*)d_in[4];
  const float* B_im = (const float*)d_in[5];
  float* out = (float*)d_out;

  if (ws_size >= (size_t)(NDIM * 64 * sizeof(float2))) {
    float2* xT = (float2*)d_ws;   // [1024 m][64 t], 512 KB
    transpose_x<<<16, 256, 0, stream>>>(x_re, x_im, xT);
    hopf_fused3<<<1024, 256, 0, stream>>>(xT, B_re, B_im, out);
  } else {
    hopf_fused_fb<<<1024, 256, 0, stream>>>(x_re, x_im, B_re, B_im, out);
  }
}

// Round 11
// 54.311 us; speedup vs baseline: 3.0898x; 1.3143x over previous
//
#include <hip/hip_runtime.h>

// HopfRNNCellTheta: T=64 < UNITS=1024 -> z[:,0] stays 0 -> A unused,
// y_t = 0.5*(B@x_t). Output = REAL part only, float32[64][1024][1024].
// out[t][n][u] = ReY[s][n], s = t+u-1023, if s>=0 else 0.
//
// r11 gemv: K-SPLIT. Block owns 4 n-rows; wave w reduces m in [256w,256w+256)
// for all 4 rows (x traffic 4x lower than r10: 512KB/CU total), B staged in
// wave-private LDS (no barriers in loop), 16-deep ping-pong global x reads
// from K0-transposed xT, single __syncthreads + 4KB LDS reduce, then r6's
// coalesced band write. Fill blocks: r6's proven byte-exact partition.

#define NDIM 1024

// ---- K0: xT[m][t] = (x_re[t][m], x_im[t][m]); 16 blocks, LDS transpose ----
__global__ __launch_bounds__(256) void transpose_x(
    const float* __restrict__ x_re, const float* __restrict__ x_im,
    float2* __restrict__ xT) {
  __shared__ float s1[64][65];
  __shared__ float s2[64][65];
  const int tid = threadIdx.x;
  const int m0 = blockIdx.x * 64;
#pragma unroll
  for (int k = 0; k < 16; ++k) {           // coalesced reads
    const int s = tid + k * 256;
    const int tr = s >> 6, j = s & 63;
    s1[tr][j] = x_re[tr * NDIM + m0 + j];
    s2[tr][j] = x_im[tr * NDIM + m0 + j];
  }
  __syncthreads();
#pragma unroll
  for (int k = 0; k < 16; ++k) {           // coalesced writes, CF LDS reads
    const int s = tid + k * 256;
    const int ml = s >> 6, t = s & 63;
    xT[(m0 + ml) * 64 + t] = make_float2(s1[t][ml], s2[t][ml]);
  }
}

// ---- K1: fused gemv + zero-fill ----
__global__ __launch_bounds__(256) void hopf_fused4(
    const float2* __restrict__ xT,
    const float* __restrict__ B_re, const float* __restrict__ B_im,
    float* __restrict__ out) {
  __shared__ float bsR[4][4][256];   // [wave][row][m'] (wave-private)
  __shared__ float bsI[4][4][256];
  __shared__ float red[4][4][64];    // [k-wave][row][t]
  const int tid = threadIdx.x;

  if (blockIdx.x >= 256) {
    // ---------- persistent zero-fill (r6-proven, byte-exact) ----------
    float4* out4 = (float4*)out;
    const float4 z = make_float4(0.f, 0.f, 0.f, 0.f);
    const int stride = 768 * 256;
    for (int q = (int)(blockIdx.x - 256) * 256 + tid; q < (1 << 24);
         q += stride) {
      const int t = q >> 18;
      const int u4 = q & 255;
      const int sb = t + 4 * u4 - 1023;    // s of word component 0
      if (sb <= -4) {                       // fully out of band (~97%)
        out4[q] = z;
      } else if (sb < 0) {                  // boundary word: mixed bytes
        float* p = out + ((long long)q << 2);
        p[0] = 0.f;
        if (sb + 1 < 0) p[1] = 0.f;
        if (sb + 2 < 0) p[2] = 0.f;         // sb+3 >= 0 always here
      }
    }
    return;
  }

  // ---------- gemv: block rows nb..nb+3; wave w reduces m-quarter w ----------
  __builtin_amdgcn_s_setprio(1);
  const int t = tid & 63;
  const int w = tid >> 6;
  const int nb = blockIdx.x * 4;
  const int mbase = w << 8;                 // 256*w

  // stage B[nb+r][mbase..mbase+256) into wave-private LDS (no barrier:
  // same-wave ds_write->ds_read ordered by compiler lgkmcnt)
#pragma unroll
  for (int r = 0; r < 4; ++r) {
    *(float4*)&bsR[w][r][t * 4] =
        *(const float4*)(B_re + (nb + r) * NDIM + mbase + t * 4);
    *(float4*)&bsI[w][r][t * 4] =
        *(const float4*)(B_im + (nb + r) * NDIM + mbase + t * 4);
  }

  float a1_0 = 0.f, a2_0 = 0.f, a1_1 = 0.f, a2_1 = 0.f;
  float a1_2 = 0.f, a2_2 = 0.f, a1_3 = 0.f, a2_3 = 0.f;
  const float2* xp = xT + (mbase << 6) + t;
  float2 xv[16], xn[16];

#define ROWFMA(R, BR, BI, X)                                            \
  do {                                                                  \
    a1_##R = fmaf(BR.x, X[0].x, a1_##R);                                \
    a2_##R = fmaf(BI.x, X[0].y, a2_##R);                                \
    a1_##R = fmaf(BR.y, X[1].x, a1_##R);                                \
    a2_##R = fmaf(BI.y, X[1].y, a2_##R);                                \
    a1_##R = fmaf(BR.z, X[2].x, a1_##R);                                \
    a2_##R = fmaf(BI.z, X[2].y, a2_##R);                                \
    a1_##R = fmaf(BR.w, X[3].x, a1_##R);                                \
    a2_##R = fmaf(BI.w, X[3].y, a2_##R);                                \
  } while (0)

#define COMP(X, MB)                                                     \
  do {                                                                  \
    _Pragma("unroll")                                                   \
    for (int q = 0; q < 4; ++q) {                                       \
      const float2* Xq = &X[q * 4];                                     \
      const float4 br0 = *(const float4*)&bsR[w][0][(MB) + q * 4];      \
      const float4 bi0 = *(const float4*)&bsI[w][0][(MB) + q * 4];      \
      ROWFMA(0, br0, bi0, Xq);                                          \
      const float4 br1 = *(const float4*)&bsR[w][1][(MB) + q * 4];      \
      const float4 bi1 = *(const float4*)&bsI[w][1][(MB) + q * 4];      \
      ROWFMA(1, br1, bi1, Xq);                                          \
      const float4 br2 = *(const float4*)&bsR[w][2][(MB) + q * 4];      \
      const float4 bi2 = *(const float4*)&bsI[w][2][(MB) + q * 4];      \
      ROWFMA(2, br2, bi2, Xq);                                          \
      const float4 br3 = *(const float4*)&bsR[w][3][(MB) + q * 4];      \
      const float4 bi3 = *(const float4*)&bsI[w][3][(MB) + q * 4];      \
      ROWFMA(3, br3, bi3, Xq);                                          \
    }                                                                   \
  } while (0)

#pragma unroll
  for (int j = 0; j < 16; ++j) xv[j] = xp[j * 64];   // chunk 0 in flight

#pragma unroll 1
  for (int m0 = 0; m0 < 256; m0 += 32) {
#pragma unroll
    for (int j = 0; j < 16; ++j) xn[j] = xp[(m0 + 16 + j) * 64];
    COMP(xv, m0);
    if (m0 + 32 < 256) {
#pragma unroll
      for (int j = 0; j < 16; ++j) xv[j] = xp[(m0 + 32 + j) * 64];
    }
    COMP(xn, m0 + 16);
  }

  // ---------- cross-wave K-reduce ----------
  red[w][0][t] = a1_0 - a2_0;
  red[w][1][t] = a1_1 - a2_1;
  red[w][2][t] = a1_2 - a2_2;
  red[w][3][t] = a1_3 - a2_3;
  __syncthreads();
  // wave w owns row nb+w
  const float yv =
      0.5f * (red[0][w][t] + red[1][w][t] + red[2][w][t] + red[3][w][t]);

  // ---------- band write: wave-uniform tt -> coalesced bursts ----------
  const long long rowoff = (long long)(nb + w) << 10;
  for (int tt = 0; tt < 64; ++tt) {
    if (t <= tt) {
      out[((long long)tt << 20) + rowoff + (1023 - tt) + t] = yv;
    }
  }
}

// ---- fallback (round-6 fused, known-passing; used only if ws too small) ----
__global__ __launch_bounds__(256) void hopf_fused_fb(
    const float* __restrict__ x_re, const float* __restrict__ x_im,
    const float* __restrict__ B_re, const float* __restrict__ B_im,
    float* __restrict__ out) {
  __shared__ float s1[64][65];
  __shared__ float s2[64][65];
  const int tid = threadIdx.x;
  if (blockIdx.x >= 256) {
    float4* out4 = (float4*)out;
    const float4 z = make_float4(0.f, 0.f, 0.f, 0.f);
    const int stride = 768 * 256;
    for (int q = (int)(blockIdx.x - 256) * 256 + tid; q < (1 << 24);
         q += stride) {
      const int t = q >> 18;
      const int u4 = q & 255;
      const int sb = t + 4 * u4 - 1023;
      if (sb <= -4) {
        out4[q] = z;
      } else if (sb < 0) {
        float* p = out + ((long long)q << 2);
        p[0] = 0.f;
        if (sb + 1 < 0) p[1] = 0.f;
        if (sb + 2 < 0) p[2] = 0.f;
      }
    }
    return;
  }
  const int t = tid & 63;
  const int ng = tid >> 6;
  const int n = blockIdx.x * 4 + ng;
  const float* p1 = B_re + n * NDIM;
  const float* p2 = B_im + n * NDIM;
  float a1 = 0.f, a2 = 0.f;
  for (int m0 = 0; m0 < NDIM; m0 += 64) {
    __syncthreads();
#pragma unroll
    for (int k = 0; k < 16; ++k) {
      const int s = tid + k * 256;
      const int tr2 = s >> 6, j = s & 63;
      s1[tr2][j] = x_re[tr2 * NDIM + m0 + j];
      s2[tr2][j] = x_im[tr2 * NDIM + m0 + j];
    }
    __syncthreads();
#pragma unroll 16
    for (int mm = 0; mm < 64; ++mm) {
      a1 = fmaf(p1[m0 + mm], s1[t][mm], a1);
      a2 = fmaf(p2[m0 + mm], s2[t][mm], a2);
    }
  }
  const float yv = 0.5f * (a1 - a2);
  const long long rowoff = (long long)(n << 10);
  for (int tt = 0; tt < 64; ++tt) {
    if (t <= tt) {
      out[((long long)tt << 20) + rowoff + (1023 - tt) + t] = yv;
    }
  }
}

extern "C" void kernel_launch(void* const* d_in, const int* in_sizes, int n_in,
                              void* d_out, int out_size, void* d_ws, size_t ws_size,
                              hipStream_t stream) {
  (void)in_sizes; (void)n_in; (void)out_size;
  const float* x_re = (const float*)d_in[0];
  const float* x_im = (const float*)d_in[1];
  const float* B_re = (const float*)d_in[4];
  const float* B_im = (const float*)d_in[5];
  float* out = (float*)d_out;

  if (ws_size >= (size_t)(NDIM * 64 * sizeof(float2))) {
    float2* xT = (float2*)d_ws;   // [1024 m][64 t], 512 KB
    transpose_x<<<16, 256, 0, stream>>>(x_re, x_im, xT);
    hopf_fused4<<<1024, 256, 0, stream>>>(xT, B_re, B_im, out);
  } else {
    hopf_fused_fb<<<1024, 256, 0, stream>>>(x_re, x_im, B_re, B_im, out);
  }
}